// Round 1
// baseline (3097.363 us; speedup 1.0000x reference)
//
#include <hip/hip_runtime.h>
#include <math.h>

// Problem constants
#define NB   64      // batch
#define NS   128     // seq len
#define NW   16      // word length (chars)
#define CD   50      // char emb dim
#define NF_  50      // filters per kernel size
#define WD   300     // word emb dim
#define COMB 450     // WD + 3*NF
#define HID  256
#define G4   1024    // 4*HID
#define NLAB 5

__device__ __forceinline__ float sigf(float x)   { return 1.0f / (1.0f + __expf(-x)); }
__device__ __forceinline__ float tanhf_(float x) { return 1.0f - 2.0f / (__expf(2.0f * x) + 1.0f); }

// ---------------- CNN + embedding concat -> x0 (8192 x 450) ----------------
__global__ __launch_bounds__(256) void cnn_embed(
    const int* __restrict__ word_ids, const int* __restrict__ char_ids,
    const float* __restrict__ word_emb, const float* __restrict__ char_emb,
    const float* __restrict__ w3, const float* __restrict__ b3,
    const float* __restrict__ w4, const float* __restrict__ b4,
    const float* __restrict__ w5, const float* __restrict__ b5,
    float* __restrict__ x0)
{
    __shared__ float ce[4][NW][CD];
    int tid  = threadIdx.x;
    int g    = tid >> 6;
    int lane = tid & 63;
    int pos  = blockIdx.x * 4 + g;          // 0..8191

    // stage char embeddings for this position
    const int* cid = char_ids + (size_t)pos * NW;
    for (int idx = lane; idx < NW * CD; idx += 64) {
        int w  = idx / CD;
        int cc = idx - w * CD;
        ce[g][w][cc] = char_emb[(size_t)cid[w] * CD + cc];
    }
    // word embedding copy (x0[:, 0:300])
    {
        int wid = word_ids[pos];
        const float* src = word_emb + (size_t)wid * WD;
        float* dst = x0 + (size_t)pos * COMB;
        for (int idx = lane; idx < WD; idx += 64) dst[idx] = src[idx];
    }
    __syncthreads();

    int f = lane;
    if (f < NF_) {
        float a3[16], a4[17], a5[16];
        float bb3 = b3[f], bb4 = b4[f], bb5 = b5[f];
#pragma unroll
        for (int p = 0; p < 16; ++p) { a3[p] = bb3; a5[p] = bb5; }
#pragma unroll
        for (int p = 0; p < 17; ++p) a4[p] = bb4;

        for (int c = 0; c < CD; ++c) {
            float w3r[3], w4r[4], w5r[5];
#pragma unroll
            for (int t = 0; t < 3; ++t) w3r[t] = w3[(t * CD + c) * NF_ + f];
#pragma unroll
            for (int t = 0; t < 4; ++t) w4r[t] = w4[(t * CD + c) * NF_ + f];
#pragma unroll
            for (int t = 0; t < 5; ++t) w5r[t] = w5[(t * CD + c) * NF_ + f];
#pragma unroll
            for (int ip = 0; ip < 16; ++ip) {
                float v = ce[g][ip][c];
#pragma unroll
                for (int t = 0; t < 3; ++t) { int p = ip + 1 - t; if (p >= 0 && p < 16) a3[p] += v * w3r[t]; }
#pragma unroll
                for (int t = 0; t < 4; ++t) { int p = ip + 2 - t; if (p >= 0 && p < 17) a4[p] += v * w4r[t]; }
#pragma unroll
                for (int t = 0; t < 5; ++t) { int p = ip + 2 - t; if (p >= 0 && p < 16) a5[p] += v * w5r[t]; }
            }
        }
        float m3 = 0.f, m4 = 0.f, m5 = 0.f;   // relu then max == max(0, max)
#pragma unroll
        for (int p = 0; p < 16; ++p) m3 = fmaxf(m3, a3[p]);
#pragma unroll
        for (int p = 0; p < 17; ++p) m4 = fmaxf(m4, a4[p]);
#pragma unroll
        for (int p = 0; p < 16; ++p) m5 = fmaxf(m5, a5[p]);
        float* dst = x0 + (size_t)pos * COMB + WD;
        dst[f] = m3; dst[NF_ + f] = m4; dst[2 * NF_ + f] = m5;
    }
}

// ------------- xg GEMM: C[8192 x 1024] = A[8192 x K] @ W[K x 1024] + bias ---
// Both directions in one launch: grid = (M/128, 16); by>>3 selects dir.
__global__ __launch_bounds__(256) void gemm_bias2(
    const float* __restrict__ A, int K,
    const float* __restrict__ Wf, const float* __restrict__ Wr,
    const float* __restrict__ bf, const float* __restrict__ br,
    float* __restrict__ Cf, float* __restrict__ Cr)
{
    int by  = blockIdx.y;
    int dir = by >> 3;
    int n0  = (by & 7) * 128;
    int m0  = blockIdx.x * 128;
    const float* W    = dir ? Wr : Wf;
    const float* bias = dir ? br : bf;
    float* C          = dir ? Cr : Cf;

    __shared__ float As[16][132];   // +4 pad: conflict-free writes, 16B-aligned reads
    __shared__ float Bs[16][128];

    int tid = threadIdx.x;
    int ka = tid & 15, ma = tid >> 4;     // A: 128 rows x 16 k
    int nb = tid & 127, kb = tid >> 7;    // B: 16 k x 128 n
    int tx = tid & 15, ty = tid >> 4;
    int row0 = ty * 8, col0 = tx * 8;

    float acc[8][8] = {};

    for (int k0 = 0; k0 < K; k0 += 16) {
#pragma unroll
        for (int i = 0; i < 8; ++i) {
            float v = 0.f;
            if (k0 + ka < K) v = A[(size_t)(m0 + ma + i * 16) * K + k0 + ka];
            As[ka][ma + i * 16] = v;
        }
#pragma unroll
        for (int i = 0; i < 8; ++i) {
            int k = kb + i * 2;
            float v = 0.f;
            if (k0 + k < K) v = W[(size_t)(k0 + k) * G4 + n0 + nb];
            Bs[k][nb] = v;
        }
        __syncthreads();
#pragma unroll
        for (int k = 0; k < 16; ++k) {
            float a[8], bv[8];
            *(float4*)&a[0]  = *(const float4*)&As[k][row0];
            *(float4*)&a[4]  = *(const float4*)&As[k][row0 + 4];
            *(float4*)&bv[0] = *(const float4*)&Bs[k][col0];
            *(float4*)&bv[4] = *(const float4*)&Bs[k][col0 + 4];
#pragma unroll
            for (int i = 0; i < 8; ++i)
#pragma unroll
                for (int j = 0; j < 8; ++j)
                    acc[i][j] += a[i] * bv[j];
        }
        __syncthreads();
    }
#pragma unroll
    for (int i = 0; i < 8; ++i) {
        size_t crow = (size_t)(m0 + row0 + i) * G4 + n0 + col0;
#pragma unroll
        for (int j = 0; j < 8; j += 4) {
            float4 o;
            o.x = acc[i][j]     + bias[n0 + col0 + j];
            o.y = acc[i][j + 1] + bias[n0 + col0 + j + 1];
            o.z = acc[i][j + 2] + bias[n0 + col0 + j + 2];
            o.w = acc[i][j + 3] + bias[n0 + col0 + j + 3];
            *(float4*)&C[crow + j] = o;
        }
    }
}

// ------------- LSTM recurrence: one block per (batch, dir) -------------------
// thread = (gate G, quad q): streams Whh[k][G*256+q*4..+3] as dwordx4 (coalesced
// 1KB/wave), h broadcast from LDS, gate exchange through LDS. 2 barriers/step.
__global__ __launch_bounds__(256) void lstm_rec(
    const float* __restrict__ xg_f, const float* __restrict__ xg_r,
    const float* __restrict__ whh_f, const float* __restrict__ whh_r,
    float* __restrict__ out)
{
    int bid = blockIdx.x;
    int b = bid >> 1, d = bid & 1;
    const float* xg = d ? xg_r : xg_f;
    const float4* W4 = (const float4*)(d ? whh_r : whh_f);  // [256 rows][256 f4]

    __shared__ alignas(16) float h_s[HID];
    __shared__ alignas(16) float gates_s[G4];

    int tid = threadIdx.x;
    int G = tid >> 6, q = tid & 63;
    int wcol4 = G * 64 + q;

    float c = 0.f;
    h_s[tid] = 0.f;
    __syncthreads();

    for (int t = 0; t < NS; ++t) {
        int te = d ? (NS - 1 - t) : t;
        size_t row = (size_t)b * NS + te;
        const float4* xg4 = (const float4*)(xg + row * G4);
        float4 acc = xg4[wcol4];
#pragma unroll 4
        for (int k = 0; k < HID; k += 4) {
            float4 h4 = *(const float4*)(h_s + k);
            float4 w0 = W4[(size_t)(k + 0) * 256 + wcol4];
            float4 w1 = W4[(size_t)(k + 1) * 256 + wcol4];
            float4 w2 = W4[(size_t)(k + 2) * 256 + wcol4];
            float4 w3 = W4[(size_t)(k + 3) * 256 + wcol4];
            acc.x += h4.x * w0.x + h4.y * w1.x + h4.z * w2.x + h4.w * w3.x;
            acc.y += h4.x * w0.y + h4.y * w1.y + h4.z * w2.y + h4.w * w3.y;
            acc.z += h4.x * w0.z + h4.y * w1.z + h4.z * w2.z + h4.w * w3.z;
            acc.w += h4.x * w0.w + h4.y * w1.w + h4.z * w2.w + h4.w * w3.w;
        }
        *(float4*)(gates_s + G * 256 + q * 4) = acc;
        __syncthreads();
        {
            int j = tid;
            float gi = gates_s[j];
            float gf = gates_s[256 + j];
            float gg = gates_s[512 + j];
            float go = gates_s[768 + j];
            float ii = sigf(gi), ff = sigf(gf), g2 = tanhf_(gg), oo = sigf(go);
            c = ff * c + ii * g2;
            float h = oo * tanhf_(c);
            h_s[j] = h;
            out[row * 512 + (size_t)d * HID + j] = h;
        }
        __syncthreads();
    }
}

// ------------- emissions: em[8192 x 5] = x2 @ out_w + out_b ------------------
__global__ __launch_bounds__(256) void emis_kernel(
    const float* __restrict__ x2, const float* __restrict__ ow,
    const float* __restrict__ ob, float* __restrict__ em)
{
    int i = blockIdx.x * blockDim.x + threadIdx.x;
    if (i >= NB * NS) return;
    const float4* xr = (const float4*)(x2 + (size_t)i * 512);
    float acc[NLAB];
#pragma unroll
    for (int l = 0; l < NLAB; ++l) acc[l] = ob[l];
    for (int k4 = 0; k4 < 128; ++k4) {
        float4 v = xr[k4];
        int k = k4 * 4;
#pragma unroll
        for (int l = 0; l < NLAB; ++l) {
            acc[l] += v.x * ow[(k + 0) * NLAB + l];
            acc[l] += v.y * ow[(k + 1) * NLAB + l];
            acc[l] += v.z * ow[(k + 2) * NLAB + l];
            acc[l] += v.w * ow[(k + 3) * NLAB + l];
        }
    }
    float* e = em + (size_t)i * NLAB;
#pragma unroll
    for (int l = 0; l < NLAB; ++l) e[l] = acc[l];
}

// ------------- CRF: numerator + forward algorithm + mean ---------------------
__device__ __forceinline__ float lse5(const float* v) {
    float m = fmaxf(fmaxf(fmaxf(v[0], v[1]), fmaxf(v[2], v[3])), v[4]);
    float s = __expf(v[0] - m) + __expf(v[1] - m) + __expf(v[2] - m) +
              __expf(v[3] - m) + __expf(v[4] - m);
    return m + __logf(s);
}

__global__ __launch_bounds__(64) void crf_kernel(
    const float* __restrict__ em, const int* __restrict__ labels,
    const int* __restrict__ lengths, const float* __restrict__ cstart,
    const float* __restrict__ cend, const float* __restrict__ ctrans,
    float* __restrict__ outp)
{
    __shared__ float tr_s[25], st_s[5], en_s[5];
    int tid = threadIdx.x;
    if (tid < 25) tr_s[tid] = ctrans[tid];
    if (tid < 5)  { st_s[tid] = cstart[tid]; en_s[tid] = cend[tid]; }
    __syncthreads();

    int b = tid;            // one lane per batch element (B=64 = one wave)
    int len = lengths[b];
    const int* tg = labels + (size_t)b * NS;
    const float* eb = em + (size_t)b * NS * NLAB;

    // numerator
    int prev = tg[0];
    float num = st_s[prev] + eb[prev];
    for (int t = 1; t < NS; ++t) {
        if (t < len) {
            int cur = tg[t];
            num += tr_s[prev * NLAB + cur] + eb[t * NLAB + cur];
            prev = cur;
        }
    }
    num += en_s[tg[len - 1]];

    // denominator (forward algorithm)
    float a[NLAB];
#pragma unroll
    for (int y = 0; y < NLAB; ++y) a[y] = st_s[y] + eb[y];
    for (int t = 1; t < NS; ++t) {
        if (t < len) {
            float na[NLAB];
#pragma unroll
            for (int y = 0; y < NLAB; ++y) {
                float v[NLAB];
#pragma unroll
                for (int x = 0; x < NLAB; ++x) v[x] = a[x] + tr_s[x * NLAB + y];
                na[y] = lse5(v) + eb[t * NLAB + y];
            }
#pragma unroll
            for (int y = 0; y < NLAB; ++y) a[y] = na[y];
        }
    }
    float v[NLAB];
#pragma unroll
    for (int y = 0; y < NLAB; ++y) v[y] = a[y] + en_s[y];
    float denom = lse5(v);

    float llh = num - denom;
#pragma unroll
    for (int off = 32; off > 0; off >>= 1) llh += __shfl_down(llh, off);
    if (tid == 0) outp[0] = -llh * (1.0f / 64.0f);
}

// ----------------------------- launcher --------------------------------------
extern "C" void kernel_launch(void* const* d_in, const int* in_sizes, int n_in,
                              void* d_out, int out_size, void* d_ws, size_t ws_size,
                              hipStream_t stream)
{
    const int*   word_ids = (const int*)d_in[0];
    const int*   char_ids = (const int*)d_in[1];
    const int*   labels   = (const int*)d_in[2];
    const int*   lengths  = (const int*)d_in[3];
    const float* word_emb = (const float*)d_in[4];
    const float* char_emb = (const float*)d_in[5];
    const float* cw3 = (const float*)d_in[6];
    const float* cb3 = (const float*)d_in[7];
    const float* cw4 = (const float*)d_in[8];
    const float* cb4 = (const float*)d_in[9];
    const float* cw5 = (const float*)d_in[10];
    const float* cb5 = (const float*)d_in[11];
    const float* out_w = (const float*)d_in[12];
    const float* out_b = (const float*)d_in[13];
    const float* crf_start = (const float*)d_in[14];
    const float* crf_end   = (const float*)d_in[15];
    const float* crf_trans = (const float*)d_in[16];
    const float* Wih_l0f = (const float*)d_in[17];
    const float* Whh_l0f = (const float*)d_in[18];
    const float* b_l0f   = (const float*)d_in[19];
    const float* Wih_l0r = (const float*)d_in[20];
    const float* Whh_l0r = (const float*)d_in[21];
    const float* b_l0r   = (const float*)d_in[22];
    const float* Wih_l1f = (const float*)d_in[23];
    const float* Whh_l1f = (const float*)d_in[24];
    const float* b_l1f   = (const float*)d_in[25];
    const float* Wih_l1r = (const float*)d_in[26];
    const float* Whh_l1r = (const float*)d_in[27];
    const float* b_l1r   = (const float*)d_in[28];

    float* ws = (float*)d_ws;
    // layout (floats): x0 | xg_f | xg_r | x1(=x2) | em   -> 24.7M floats = 98.8 MB
    float* x0   = ws;                       // 8192*450   = 3,686,400
    float* xg_f = x0 + 3686400;             // 8192*1024  = 8,388,608
    float* xg_r = xg_f + 8388608;
    float* x1   = xg_r + 8388608;           // 8192*512   = 4,194,304
    float* x2   = x1;                       // overlays x1 (x1 dead after gemm l1)
    float* em   = x1 + 4194304;             // 8192*5     = 40,960

    dim3 gGemm(64, 16);

    cnn_embed<<<2048, 256, 0, stream>>>(word_ids, char_ids, word_emb, char_emb,
                                        cw3, cb3, cw4, cb4, cw5, cb5, x0);

    gemm_bias2<<<gGemm, 256, 0, stream>>>(x0, COMB, Wih_l0f, Wih_l0r, b_l0f, b_l0r, xg_f, xg_r);
    lstm_rec<<<128, 256, 0, stream>>>(xg_f, xg_r, Whh_l0f, Whh_l0r, x1);

    gemm_bias2<<<gGemm, 256, 0, stream>>>(x1, 512, Wih_l1f, Wih_l1r, b_l1f, b_l1r, xg_f, xg_r);
    lstm_rec<<<128, 256, 0, stream>>>(xg_f, xg_r, Whh_l1f, Whh_l1r, x2);

    emis_kernel<<<32, 256, 0, stream>>>(x2, out_w, out_b, em);
    crf_kernel<<<1, 64, 0, stream>>>(em, labels, lengths, crf_start, crf_end, crf_trans,
                                     (float*)d_out);
}

// Round 2
// 2085.259 us; speedup vs baseline: 1.4854x; 1.4854x over previous
//
#include <hip/hip_runtime.h>
#include <math.h>
#include <stdint.h>

// Problem constants
#define NB   64      // batch
#define NS   128     // seq len
#define NW   16      // word length (chars)
#define CD   50      // char emb dim
#define NF_  50      // filters per kernel size
#define WD   300     // word emb dim
#define COMB 450     // WD + 3*NF
#define HID  256
#define G4   1024    // 4*HID
#define NLAB 5

__device__ __forceinline__ float sigf(float x)   { return 1.0f / (1.0f + __expf(-x)); }
__device__ __forceinline__ float tanhf_(float x) { return 1.0f - 2.0f / (__expf(2.0f * x) + 1.0f); }

// ---------------- CNN + embedding concat -> x0 (8192 x 450) ----------------
__global__ __launch_bounds__(256) void cnn_embed(
    const int* __restrict__ word_ids, const int* __restrict__ char_ids,
    const float* __restrict__ word_emb, const float* __restrict__ char_emb,
    const float* __restrict__ w3, const float* __restrict__ b3,
    const float* __restrict__ w4, const float* __restrict__ b4,
    const float* __restrict__ w5, const float* __restrict__ b5,
    float* __restrict__ x0)
{
    __shared__ float ce[4][NW][CD];
    int tid  = threadIdx.x;
    int g    = tid >> 6;
    int lane = tid & 63;
    int pos  = blockIdx.x * 4 + g;          // 0..8191

    const int* cid = char_ids + (size_t)pos * NW;
    for (int idx = lane; idx < NW * CD; idx += 64) {
        int w  = idx / CD;
        int cc = idx - w * CD;
        ce[g][w][cc] = char_emb[(size_t)cid[w] * CD + cc];
    }
    {
        int wid = word_ids[pos];
        const float* src = word_emb + (size_t)wid * WD;
        float* dst = x0 + (size_t)pos * COMB;
        for (int idx = lane; idx < WD; idx += 64) dst[idx] = src[idx];
    }
    __syncthreads();

    int f = lane;
    if (f < NF_) {
        float a3[16], a4[17], a5[16];
        float bb3 = b3[f], bb4 = b4[f], bb5 = b5[f];
#pragma unroll
        for (int p = 0; p < 16; ++p) { a3[p] = bb3; a5[p] = bb5; }
#pragma unroll
        for (int p = 0; p < 17; ++p) a4[p] = bb4;

        for (int c = 0; c < CD; ++c) {
            float w3r[3], w4r[4], w5r[5];
#pragma unroll
            for (int t = 0; t < 3; ++t) w3r[t] = w3[(t * CD + c) * NF_ + f];
#pragma unroll
            for (int t = 0; t < 4; ++t) w4r[t] = w4[(t * CD + c) * NF_ + f];
#pragma unroll
            for (int t = 0; t < 5; ++t) w5r[t] = w5[(t * CD + c) * NF_ + f];
#pragma unroll
            for (int ip = 0; ip < 16; ++ip) {
                float v = ce[g][ip][c];
#pragma unroll
                for (int t = 0; t < 3; ++t) { int p = ip + 1 - t; if (p >= 0 && p < 16) a3[p] += v * w3r[t]; }
#pragma unroll
                for (int t = 0; t < 4; ++t) { int p = ip + 2 - t; if (p >= 0 && p < 17) a4[p] += v * w4r[t]; }
#pragma unroll
                for (int t = 0; t < 5; ++t) { int p = ip + 2 - t; if (p >= 0 && p < 16) a5[p] += v * w5r[t]; }
            }
        }
        float m3 = 0.f, m4 = 0.f, m5 = 0.f;
#pragma unroll
        for (int p = 0; p < 16; ++p) m3 = fmaxf(m3, a3[p]);
#pragma unroll
        for (int p = 0; p < 17; ++p) m4 = fmaxf(m4, a4[p]);
#pragma unroll
        for (int p = 0; p < 16; ++p) m5 = fmaxf(m5, a5[p]);
        float* dst = x0 + (size_t)pos * COMB + WD;
        dst[f] = m3; dst[NF_ + f] = m4; dst[2 * NF_ + f] = m5;
    }
}

// ------------- xg GEMM: C[8192 x 1024] = A[8192 x K] @ W[K x 1024] + bias ---
__global__ __launch_bounds__(256) void gemm_bias2(
    const float* __restrict__ A, int K,
    const float* __restrict__ Wf, const float* __restrict__ Wr,
    const float* __restrict__ bf, const float* __restrict__ br,
    float* __restrict__ Cf, float* __restrict__ Cr)
{
    int by  = blockIdx.y;
    int dir = by >> 3;
    int n0  = (by & 7) * 128;
    int m0  = blockIdx.x * 128;
    const float* W    = dir ? Wr : Wf;
    const float* bias = dir ? br : bf;
    float* C          = dir ? Cr : Cf;

    __shared__ float As[16][132];
    __shared__ float Bs[16][128];

    int tid = threadIdx.x;
    int ka = tid & 15, ma = tid >> 4;
    int nb = tid & 127, kb = tid >> 7;
    int tx = tid & 15, ty = tid >> 4;
    int row0 = ty * 8, col0 = tx * 8;

    float acc[8][8] = {};

    for (int k0 = 0; k0 < K; k0 += 16) {
#pragma unroll
        for (int i = 0; i < 8; ++i) {
            float v = 0.f;
            if (k0 + ka < K) v = A[(size_t)(m0 + ma + i * 16) * K + k0 + ka];
            As[ka][ma + i * 16] = v;
        }
#pragma unroll
        for (int i = 0; i < 8; ++i) {
            int k = kb + i * 2;
            float v = 0.f;
            if (k0 + k < K) v = W[(size_t)(k0 + k) * G4 + n0 + nb];
            Bs[k][nb] = v;
        }
        __syncthreads();
#pragma unroll
        for (int k = 0; k < 16; ++k) {
            float a[8], bv[8];
            *(float4*)&a[0]  = *(const float4*)&As[k][row0];
            *(float4*)&a[4]  = *(const float4*)&As[k][row0 + 4];
            *(float4*)&bv[0] = *(const float4*)&Bs[k][col0];
            *(float4*)&bv[4] = *(const float4*)&Bs[k][col0 + 4];
#pragma unroll
            for (int i = 0; i < 8; ++i)
#pragma unroll
                for (int j = 0; j < 8; ++j)
                    acc[i][j] += a[i] * bv[j];
        }
        __syncthreads();
    }
#pragma unroll
    for (int i = 0; i < 8; ++i) {
        size_t crow = (size_t)(m0 + row0 + i) * G4 + n0 + col0;
#pragma unroll
        for (int j = 0; j < 8; j += 4) {
            float4 o;
            o.x = acc[i][j]     + bias[n0 + col0 + j];
            o.y = acc[i][j + 1] + bias[n0 + col0 + j + 1];
            o.z = acc[i][j + 2] + bias[n0 + col0 + j + 2];
            o.w = acc[i][j + 3] + bias[n0 + col0 + j + 3];
            *(float4*)&C[crow + j] = o;
        }
    }
}

// ------------- Whh bf16 pack: W[256][1024] f32 -> P[64][512][4] u32 ----------
// P[k4][cp][kk] = bf16(W[4k4+kk][2cp+1])<<16 | bf16(W[4k4+kk][2cp])
__device__ __forceinline__ uint32_t bf16r(float x) {
    uint32_t u = __float_as_uint(x);
    u += 0x7fffu + ((u >> 16) & 1u);      // round-to-nearest-even
    return u >> 16;
}

__global__ __launch_bounds__(256) void pack_whh(
    const float* __restrict__ W, uint32_t* __restrict__ P)
{
    int idx = blockIdx.x * 256 + threadIdx.x;     // 64*512*4 = 131072
    if (idx >= 64 * 512 * 4) return;
    int kk = idx & 3, cp = (idx >> 2) & 511, k4 = idx >> 11;
    int k = k4 * 4 + kk;
    float lo = W[(size_t)k * G4 + 2 * cp];
    float hi = W[(size_t)k * G4 + 2 * cp + 1];
    P[idx] = (bf16r(hi) << 16) | bf16r(lo);
}

// ------------- LSTM recurrence v2: 512 thr/block, bf16 packed Whh ------------
// Block per (batch, dir). Thread owns gate-columns {2t, 2t+1}. Per k4 step:
// one ds_read_b128 (h quad) + one dwordx4 (8 bf16 weights) + 8 unpack + 8 FMA.
__global__ __launch_bounds__(512) void lstm_rec2(
    const float* __restrict__ xg_f, const float* __restrict__ xg_r,
    const uint32_t* __restrict__ Pf, const uint32_t* __restrict__ Pr,
    float* __restrict__ out)
{
    int bid = blockIdx.x;
    int b = bid >> 1, d = bid & 1;
    const float* xg = d ? xg_r : xg_f;
    const uint32_t* P = d ? Pr : Pf;     // [64][512][4]

    __shared__ alignas(16) float h_s[HID];
    __shared__ alignas(16) float gates_s[G4];

    int tid = threadIdx.x;               // colpair 0..511
    int col0 = 2 * tid;

    float c = 0.f;                       // cell state (threads 0..255 only)
    if (tid < HID) h_s[tid] = 0.f;
    __syncthreads();

    for (int t = 0; t < NS; ++t) {
        int te = d ? (NS - 1 - t) : t;
        size_t row = (size_t)b * NS + te;
        float2 acc = *(const float2*)(xg + row * G4 + col0);

#pragma unroll 4
        for (int k4 = 0; k4 < 64; ++k4) {
            float4 h4 = *(const float4*)(h_s + k4 * 4);
            uint4 w = *(const uint4*)(P + ((size_t)k4 * 512 + tid) * 4);
            acc.x += h4.x * __uint_as_float(w.x << 16);
            acc.y += h4.x * __uint_as_float(w.x & 0xffff0000u);
            acc.x += h4.y * __uint_as_float(w.y << 16);
            acc.y += h4.y * __uint_as_float(w.y & 0xffff0000u);
            acc.x += h4.z * __uint_as_float(w.z << 16);
            acc.y += h4.z * __uint_as_float(w.z & 0xffff0000u);
            acc.x += h4.w * __uint_as_float(w.w << 16);
            acc.y += h4.w * __uint_as_float(w.w & 0xffff0000u);
        }
        *(float2*)(gates_s + col0) = acc;
        __syncthreads();
        if (tid < HID) {
            int j = tid;
            float gi = gates_s[j];
            float gf = gates_s[256 + j];
            float gg = gates_s[512 + j];
            float go = gates_s[768 + j];
            float ii = sigf(gi), ff = sigf(gf), g2 = tanhf_(gg), oo = sigf(go);
            c = ff * c + ii * g2;
            float h = oo * tanhf_(c);
            h_s[j] = h;
            out[row * 512 + (size_t)d * HID + j] = h;
        }
        __syncthreads();
    }
}

// ------------- emissions: em[8192 x 5] = x2 @ out_w + out_b ------------------
__global__ __launch_bounds__(256) void emis_kernel(
    const float* __restrict__ x2, const float* __restrict__ ow,
    const float* __restrict__ ob, float* __restrict__ em)
{
    int i = blockIdx.x * blockDim.x + threadIdx.x;
    if (i >= NB * NS) return;
    const float4* xr = (const float4*)(x2 + (size_t)i * 512);
    float acc[NLAB];
#pragma unroll
    for (int l = 0; l < NLAB; ++l) acc[l] = ob[l];
    for (int k4 = 0; k4 < 128; ++k4) {
        float4 v = xr[k4];
        int k = k4 * 4;
#pragma unroll
        for (int l = 0; l < NLAB; ++l) {
            acc[l] += v.x * ow[(k + 0) * NLAB + l];
            acc[l] += v.y * ow[(k + 1) * NLAB + l];
            acc[l] += v.z * ow[(k + 2) * NLAB + l];
            acc[l] += v.w * ow[(k + 3) * NLAB + l];
        }
    }
    float* e = em + (size_t)i * NLAB;
#pragma unroll
    for (int l = 0; l < NLAB; ++l) e[l] = acc[l];
}

// ------------- CRF: numerator + forward algorithm + mean ---------------------
__device__ __forceinline__ float lse5(const float* v) {
    float m = fmaxf(fmaxf(fmaxf(v[0], v[1]), fmaxf(v[2], v[3])), v[4]);
    float s = __expf(v[0] - m) + __expf(v[1] - m) + __expf(v[2] - m) +
              __expf(v[3] - m) + __expf(v[4] - m);
    return m + __logf(s);
}

__global__ __launch_bounds__(64) void crf_kernel(
    const float* __restrict__ em, const int* __restrict__ labels,
    const int* __restrict__ lengths, const float* __restrict__ cstart,
    const float* __restrict__ cend, const float* __restrict__ ctrans,
    float* __restrict__ outp)
{
    __shared__ float tr_s[25], st_s[5], en_s[5];
    int tid = threadIdx.x;
    if (tid < 25) tr_s[tid] = ctrans[tid];
    if (tid < 5)  { st_s[tid] = cstart[tid]; en_s[tid] = cend[tid]; }
    __syncthreads();

    int b = tid;
    int len = lengths[b];
    const int* tg = labels + (size_t)b * NS;
    const float* eb = em + (size_t)b * NS * NLAB;

    int prev = tg[0];
    float num = st_s[prev] + eb[prev];
    for (int t = 1; t < NS; ++t) {
        if (t < len) {
            int cur = tg[t];
            num += tr_s[prev * NLAB + cur] + eb[t * NLAB + cur];
            prev = cur;
        }
    }
    num += en_s[tg[len - 1]];

    float a[NLAB];
#pragma unroll
    for (int y = 0; y < NLAB; ++y) a[y] = st_s[y] + eb[y];
    for (int t = 1; t < NS; ++t) {
        if (t < len) {
            float na[NLAB];
#pragma unroll
            for (int y = 0; y < NLAB; ++y) {
                float v[NLAB];
#pragma unroll
                for (int x = 0; x < NLAB; ++x) v[x] = a[x] + tr_s[x * NLAB + y];
                na[y] = lse5(v) + eb[t * NLAB + y];
            }
#pragma unroll
            for (int y = 0; y < NLAB; ++y) a[y] = na[y];
        }
    }
    float v[NLAB];
#pragma unroll
    for (int y = 0; y < NLAB; ++y) v[y] = a[y] + en_s[y];
    float denom = lse5(v);

    float llh = num - denom;
#pragma unroll
    for (int off = 32; off > 0; off >>= 1) llh += __shfl_down(llh, off);
    if (tid == 0) outp[0] = -llh * (1.0f / 64.0f);
}

// ----------------------------- launcher --------------------------------------
extern "C" void kernel_launch(void* const* d_in, const int* in_sizes, int n_in,
                              void* d_out, int out_size, void* d_ws, size_t ws_size,
                              hipStream_t stream)
{
    const int*   word_ids = (const int*)d_in[0];
    const int*   char_ids = (const int*)d_in[1];
    const int*   labels   = (const int*)d_in[2];
    const int*   lengths  = (const int*)d_in[3];
    const float* word_emb = (const float*)d_in[4];
    const float* char_emb = (const float*)d_in[5];
    const float* cw3 = (const float*)d_in[6];
    const float* cb3 = (const float*)d_in[7];
    const float* cw4 = (const float*)d_in[8];
    const float* cb4 = (const float*)d_in[9];
    const float* cw5 = (const float*)d_in[10];
    const float* cb5 = (const float*)d_in[11];
    const float* out_w = (const float*)d_in[12];
    const float* out_b = (const float*)d_in[13];
    const float* crf_start = (const float*)d_in[14];
    const float* crf_end   = (const float*)d_in[15];
    const float* crf_trans = (const float*)d_in[16];
    const float* Wih_l0f = (const float*)d_in[17];
    const float* Whh_l0f = (const float*)d_in[18];
    const float* b_l0f   = (const float*)d_in[19];
    const float* Wih_l0r = (const float*)d_in[20];
    const float* Whh_l0r = (const float*)d_in[21];
    const float* b_l0r   = (const float*)d_in[22];
    const float* Wih_l1f = (const float*)d_in[23];
    const float* Whh_l1f = (const float*)d_in[24];
    const float* b_l1f   = (const float*)d_in[25];
    const float* Wih_l1r = (const float*)d_in[26];
    const float* Whh_l1r = (const float*)d_in[27];
    const float* b_l1r   = (const float*)d_in[28];

    float* ws = (float*)d_ws;
    // layout (floats): x0 | xg_f | xg_r | x1(=x2) | em   -> 24.7M floats = 98.8 MB
    float* x0   = ws;                       // 8192*450   = 3,686,400
    float* xg_f = x0 + 3686400;             // 8192*1024  = 8,388,608
    float* xg_r = xg_f + 8388608;
    float* x1   = xg_r + 8388608;           // 8192*512   = 4,194,304
    float* x2   = x1;
    float* em   = x1 + 4194304;             // 8192*5     = 40,960

    // packed Whh (bf16) overlays x0 (dead after gemm l0): 4 x 131072 u32 = 2 MB
    uint32_t* Pl0f = (uint32_t*)x0;
    uint32_t* Pl0r = Pl0f + 131072;
    uint32_t* Pl1f = Pl0r + 131072;
    uint32_t* Pl1r = Pl1f + 131072;

    dim3 gGemm(64, 16);

    cnn_embed<<<2048, 256, 0, stream>>>(word_ids, char_ids, word_emb, char_emb,
                                        cw3, cb3, cw4, cb4, cw5, cb5, x0);

    gemm_bias2<<<gGemm, 256, 0, stream>>>(x0, COMB, Wih_l0f, Wih_l0r, b_l0f, b_l0r, xg_f, xg_r);

    pack_whh<<<512, 256, 0, stream>>>(Whh_l0f, Pl0f);
    pack_whh<<<512, 256, 0, stream>>>(Whh_l0r, Pl0r);
    pack_whh<<<512, 256, 0, stream>>>(Whh_l1f, Pl1f);
    pack_whh<<<512, 256, 0, stream>>>(Whh_l1r, Pl1r);

    lstm_rec2<<<128, 512, 0, stream>>>(xg_f, xg_r, Pl0f, Pl0r, x1);

    gemm_bias2<<<gGemm, 256, 0, stream>>>(x1, 512, Wih_l1f, Wih_l1r, b_l1f, b_l1r, xg_f, xg_r);

    lstm_rec2<<<128, 512, 0, stream>>>(xg_f, xg_r, Pl1f, Pl1r, x2);

    emis_kernel<<<32, 256, 0, stream>>>(x2, out_w, out_b, em);
    crf_kernel<<<1, 64, 0, stream>>>(em, labels, lengths, crf_start, crf_end, crf_trans,
                                     (float*)d_out);
}

// Round 3
// 1743.983 us; speedup vs baseline: 1.7760x; 1.1957x over previous
//
#include <hip/hip_runtime.h>
#include <hip/hip_fp16.h>
#include <math.h>
#include <stdint.h>

// Problem constants
#define NB   64      // batch
#define NS   128     // seq len
#define NW   16      // word length (chars)
#define CD   50      // char emb dim
#define NF_  50      // filters per kernel size
#define WD   300     // word emb dim
#define COMB 450     // WD + 3*NF  (even -> 225 f16 pairs)
#define HID  256
#define G4   1024    // 4*HID
#define NLAB 5

typedef _Float16 h2_t __attribute__((ext_vector_type(2)));

__device__ __forceinline__ float sigf(float x)   { return 1.0f / (1.0f + __expf(-x)); }
__device__ __forceinline__ float tanhf_(float x) { return 1.0f - 2.0f / (__expf(2.0f * x) + 1.0f); }

__device__ __forceinline__ float dot2f(uint32_t a, uint32_t b, float c) {
#if __has_builtin(__builtin_amdgcn_fdot2)
    return __builtin_amdgcn_fdot2(__builtin_bit_cast(h2_t, a),
                                  __builtin_bit_cast(h2_t, b), c, false);
#else
    h2_t ah = __builtin_bit_cast(h2_t, a), bh = __builtin_bit_cast(h2_t, b);
    return c + (float)ah[0] * (float)bh[0] + (float)ah[1] * (float)bh[1];
#endif
}

__device__ __forceinline__ uint32_t packh2(float lo, float hi) {
    __half l = __float2half(lo), h = __float2half(hi);
    return ((uint32_t)__half_as_ushort(h) << 16) | (uint32_t)__half_as_ushort(l);
}

// ---------------- CNN + embedding concat -> x0p (8192 x 225 u32, f16 pairs) --
__global__ __launch_bounds__(256) void cnn_embed(
    const int* __restrict__ word_ids, const int* __restrict__ char_ids,
    const float* __restrict__ word_emb, const float* __restrict__ char_emb,
    const float* __restrict__ w3, const float* __restrict__ b3,
    const float* __restrict__ w4, const float* __restrict__ b4,
    const float* __restrict__ w5, const float* __restrict__ b5,
    uint32_t* __restrict__ x0p)
{
    __shared__ float ce[4][NW][CD];
    __shared__ float cv[4][152];            // conv outputs per position
    int tid  = threadIdx.x;
    int g    = tid >> 6;
    int lane = tid & 63;
    int pos  = blockIdx.x * 4 + g;          // 0..8191

    const int* cid = char_ids + (size_t)pos * NW;
    for (int idx = lane; idx < NW * CD; idx += 64) {
        int w  = idx / CD;
        int cc = idx - w * CD;
        ce[g][w][cc] = char_emb[(size_t)cid[w] * CD + cc];
    }
    // word embedding -> packed pairs 0..149
    {
        int wid = word_ids[pos];
        const float* src = word_emb + (size_t)wid * WD;
        uint32_t* dst = x0p + (size_t)pos * 225;
        for (int idx = lane; idx < 150; idx += 64) {
            float2 v = *(const float2*)(src + 2 * idx);
            dst[idx] = packh2(v.x, v.y);
        }
    }
    __syncthreads();

    int f = lane;
    if (f < NF_) {
        float a3[16], a4[17], a5[16];
        float bb3 = b3[f], bb4 = b4[f], bb5 = b5[f];
#pragma unroll
        for (int p = 0; p < 16; ++p) { a3[p] = bb3; a5[p] = bb5; }
#pragma unroll
        for (int p = 0; p < 17; ++p) a4[p] = bb4;

        for (int c = 0; c < CD; ++c) {
            float w3r[3], w4r[4], w5r[5];
#pragma unroll
            for (int t = 0; t < 3; ++t) w3r[t] = w3[(t * CD + c) * NF_ + f];
#pragma unroll
            for (int t = 0; t < 4; ++t) w4r[t] = w4[(t * CD + c) * NF_ + f];
#pragma unroll
            for (int t = 0; t < 5; ++t) w5r[t] = w5[(t * CD + c) * NF_ + f];
#pragma unroll
            for (int ip = 0; ip < 16; ++ip) {
                float v = ce[g][ip][c];
#pragma unroll
                for (int t = 0; t < 3; ++t) { int p = ip + 1 - t; if (p >= 0 && p < 16) a3[p] += v * w3r[t]; }
#pragma unroll
                for (int t = 0; t < 4; ++t) { int p = ip + 2 - t; if (p >= 0 && p < 17) a4[p] += v * w4r[t]; }
#pragma unroll
                for (int t = 0; t < 5; ++t) { int p = ip + 2 - t; if (p >= 0 && p < 16) a5[p] += v * w5r[t]; }
            }
        }
        float m3 = 0.f, m4 = 0.f, m5 = 0.f;
#pragma unroll
        for (int p = 0; p < 16; ++p) m3 = fmaxf(m3, a3[p]);
#pragma unroll
        for (int p = 0; p < 17; ++p) m4 = fmaxf(m4, a4[p]);
#pragma unroll
        for (int p = 0; p < 16; ++p) m5 = fmaxf(m5, a5[p]);
        cv[g][f] = m3; cv[g][50 + f] = m4; cv[g][100 + f] = m5;
    }
    __syncthreads();
    // pack conv pairs 150..224
    {
        uint32_t* dst = x0p + (size_t)pos * 225 + 150;
        for (int idx = lane; idx < 75; idx += 64)
            dst[idx] = packh2(cv[g][2 * idx], cv[g][2 * idx + 1]);
    }
}

// ------------- weight packs ---------------------------------------------------
// Wih: P[kp*1024 + n] = h2(W[2kp][n], W[2kp+1][n])
__global__ __launch_bounds__(256) void pack_wih(
    const float* __restrict__ W, int K, uint32_t* __restrict__ P)
{
    int idx = blockIdx.x * 256 + threadIdx.x;
    int K2 = K >> 1;
    if (idx >= K2 * 1024) return;
    int n = idx & 1023, kp = idx >> 10;
    int k0 = 2 * kp;
    float lo = W[(size_t)k0 * 1024 + n];
    float hi = W[(size_t)(k0 + 1) * 1024 + n];
    P[idx] = packh2(lo, hi);
}

// Whh: P[(kq*1024+col)*4+kk] = h2(W[8kq+2kk][col], W[8kq+2kk+1][col])
__global__ __launch_bounds__(256) void pack_whh(
    const float* __restrict__ W, uint32_t* __restrict__ P)
{
    int idx = blockIdx.x * 256 + threadIdx.x;     // 32*1024*4 = 131072
    if (idx >= 131072) return;
    int kk = idx & 3, col = (idx >> 2) & 1023, kq = idx >> 12;
    int k = kq * 8 + kk * 2;
    float lo = W[(size_t)k * G4 + col];
    float hi = W[(size_t)(k + 1) * G4 + col];
    P[idx] = packh2(lo, hi);
}

// ------------- xg GEMM (f16 dot2): C[8192 x 1024] = Ap @ Wp + bias -----------
__global__ __launch_bounds__(256) void gemm_f16(
    const uint32_t* __restrict__ Ap, int K2,
    const uint32_t* __restrict__ Wpf, const uint32_t* __restrict__ Wpr,
    const float* __restrict__ bf, const float* __restrict__ br,
    float* __restrict__ Cf, float* __restrict__ Cr)
{
    int by  = blockIdx.y;
    int dir = by >> 3;
    int n0  = (by & 7) * 128;
    int m0  = blockIdx.x * 128;
    const uint32_t* Wp = dir ? Wpr : Wpf;
    const float* bias  = dir ? br : bf;
    float* C           = dir ? Cr : Cf;

    __shared__ uint32_t As[8][132];
    __shared__ uint32_t Bs[8][132];

    int tid = threadIdx.x;
    int ka = tid & 7,  ma = tid >> 3;       // A: 8 kp x 32 rows (x4)
    int kb = tid >> 7, nb = tid & 127;      // B: 2 kp (x4) x 128 n
    int tx = tid & 15, ty = tid >> 4;
    int row0 = ty * 8, col0 = tx * 8;

    float acc[8][8] = {};

    for (int kp0 = 0; kp0 < K2; kp0 += 8) {
#pragma unroll
        for (int i = 0; i < 4; ++i) {
            uint32_t v = 0;
            if (kp0 + ka < K2) v = Ap[(size_t)(m0 + ma + 32 * i) * K2 + kp0 + ka];
            As[ka][ma + 32 * i] = v;
        }
#pragma unroll
        for (int i = 0; i < 4; ++i) {
            int kp = kb + 2 * i;
            uint32_t v = 0;
            if (kp0 + kp < K2) v = Wp[(size_t)(kp0 + kp) * G4 + n0 + nb];
            Bs[kp][nb] = v;
        }
        __syncthreads();
#pragma unroll
        for (int kp = 0; kp < 8; ++kp) {
            uint32_t a[8], b[8];
            *(uint4*)&a[0] = *(const uint4*)&As[kp][row0];
            *(uint4*)&a[4] = *(const uint4*)&As[kp][row0 + 4];
            *(uint4*)&b[0] = *(const uint4*)&Bs[kp][col0];
            *(uint4*)&b[4] = *(const uint4*)&Bs[kp][col0 + 4];
#pragma unroll
            for (int i = 0; i < 8; ++i)
#pragma unroll
                for (int j = 0; j < 8; ++j)
                    acc[i][j] = dot2f(a[i], b[j], acc[i][j]);
        }
        __syncthreads();
    }
#pragma unroll
    for (int i = 0; i < 8; ++i) {
        size_t crow = (size_t)(m0 + row0 + i) * G4 + n0 + col0;
#pragma unroll
        for (int j = 0; j < 8; j += 4) {
            float4 o;
            o.x = acc[i][j]     + bias[n0 + col0 + j];
            o.y = acc[i][j + 1] + bias[n0 + col0 + j + 1];
            o.z = acc[i][j + 2] + bias[n0 + col0 + j + 2];
            o.w = acc[i][j + 3] + bias[n0 + col0 + j + 3];
            *(float4*)&C[crow + j] = o;
        }
    }
}

// ------------- LSTM recurrence v3: 64 blocks (batch-pair x dir), f16 dot2 ----
// Thread t owns gate columns {2t,2t+1} for BOTH batch rows (weights reused 2x).
// h kept packed f16 in LDS; per k-octet: 2 dwordx4 weight loads (L2),
// 2 broadcast ds_read_b128 (h), 16 v_dot2_f32_f16.
__global__ __launch_bounds__(512) void lstm_rec3(
    const float* __restrict__ xg_f, const float* __restrict__ xg_r,
    const uint32_t* __restrict__ Pf, const uint32_t* __restrict__ Pr,
    uint32_t* __restrict__ outp)   // [8192][256] u32: row*256 + d*128 + jp
{
    int bid = blockIdx.x;           // 64 = 32 batch-pairs x 2 dirs
    int bp = bid >> 1, d = bid & 1;
    int b0 = 2 * bp;
    const float* xg = d ? xg_r : xg_f;
    const uint32_t* P = d ? Pr : Pf;   // [32][1024][4] u32

    __shared__ alignas(16) uint32_t hp[2][128];   // h packed f16 pairs
    __shared__ float gates[2][G4];

    int t = threadIdx.x;            // 0..511
    int c0 = 2 * t;

    if (t < 256) hp[t >> 7][t & 127] = 0;
    float cst = 0.f;                // cell state for (bb = t>>8, j = t&255)
    __syncthreads();

    for (int s = 0; s < NS; ++s) {
        int te = d ? (NS - 1 - s) : s;
        size_t r0 = ((size_t)b0 * NS + te) * G4;
        size_t r1 = r0 + (size_t)NS * G4;
        float2 xa = *(const float2*)(xg + r0 + c0);
        float2 xb = *(const float2*)(xg + r1 + c0);
        float a00 = xa.x, a01 = xa.y, a10 = xb.x, a11 = xb.y;

        const uint32_t* pw = P + 8 * (size_t)t;
#pragma unroll 4
        for (int kq = 0; kq < 32; ++kq) {
            uint4 w0 = *(const uint4*)(pw);        // col c0,   4 k-pairs
            uint4 w1 = *(const uint4*)(pw + 4);    // col c0+1
            uint4 h0 = *(const uint4*)(&hp[0][kq * 4]);
            uint4 h1 = *(const uint4*)(&hp[1][kq * 4]);
            a00 = dot2f(h0.x, w0.x, a00); a01 = dot2f(h0.x, w1.x, a01);
            a10 = dot2f(h1.x, w0.x, a10); a11 = dot2f(h1.x, w1.x, a11);
            a00 = dot2f(h0.y, w0.y, a00); a01 = dot2f(h0.y, w1.y, a01);
            a10 = dot2f(h1.y, w0.y, a10); a11 = dot2f(h1.y, w1.y, a11);
            a00 = dot2f(h0.z, w0.z, a00); a01 = dot2f(h0.z, w1.z, a01);
            a10 = dot2f(h1.z, w0.z, a10); a11 = dot2f(h1.z, w1.z, a11);
            a00 = dot2f(h0.w, w0.w, a00); a01 = dot2f(h0.w, w1.w, a01);
            a10 = dot2f(h1.w, w0.w, a10); a11 = dot2f(h1.w, w1.w, a11);
            pw += 4096;
        }
        *(float2*)&gates[0][c0] = make_float2(a00, a01);
        *(float2*)&gates[1][c0] = make_float2(a10, a11);
        __syncthreads();
        {
            int bb = t >> 8, j = t & 255;
            float gi = gates[bb][j];
            float gf = gates[bb][256 + j];
            float gg = gates[bb][512 + j];
            float go = gates[bb][768 + j];
            float ii = sigf(gi), ff = sigf(gf), g2 = tanhf_(gg), oo = sigf(go);
            cst = ff * cst + ii * g2;
            float h = oo * tanhf_(cst);
            float hx = __shfl_xor(h, 1);
            if (!(t & 1)) {
                uint32_t pk = packh2(h, hx);
                hp[bb][j >> 1] = pk;
                size_t row = (size_t)(b0 + bb) * NS + te;
                outp[row * 256 + d * 128 + (j >> 1)] = pk;
            }
        }
        __syncthreads();
    }
}

// ------------- emissions: em[8192 x 5] = x2p @ out_w + out_b -----------------
__global__ __launch_bounds__(256) void emis_kernel(
    const uint32_t* __restrict__ x2p, const float* __restrict__ ow,
    const float* __restrict__ ob, float* __restrict__ em)
{
    int i = blockIdx.x * blockDim.x + threadIdx.x;
    if (i >= NB * NS) return;
    const uint32_t* xr = x2p + (size_t)i * 256;
    float acc[NLAB];
#pragma unroll
    for (int l = 0; l < NLAB; ++l) acc[l] = ob[l];
    for (int p = 0; p < 256; ++p) {
        h2_t hv = __builtin_bit_cast(h2_t, xr[p]);
        float lo = (float)hv[0], hi = (float)hv[1];
        int k = 2 * p;
#pragma unroll
        for (int l = 0; l < NLAB; ++l)
            acc[l] += lo * ow[(size_t)k * NLAB + l] + hi * ow[(size_t)(k + 1) * NLAB + l];
    }
    float* e = em + (size_t)i * NLAB;
#pragma unroll
    for (int l = 0; l < NLAB; ++l) e[l] = acc[l];
}

// ------------- CRF: numerator + forward algorithm + mean ---------------------
__device__ __forceinline__ float lse5(const float* v) {
    float m = fmaxf(fmaxf(fmaxf(v[0], v[1]), fmaxf(v[2], v[3])), v[4]);
    float s = __expf(v[0] - m) + __expf(v[1] - m) + __expf(v[2] - m) +
              __expf(v[3] - m) + __expf(v[4] - m);
    return m + __logf(s);
}

__global__ __launch_bounds__(64) void crf_kernel(
    const float* __restrict__ em, const int* __restrict__ labels,
    const int* __restrict__ lengths, const float* __restrict__ cstart,
    const float* __restrict__ cend, const float* __restrict__ ctrans,
    float* __restrict__ outp)
{
    __shared__ float tr_s[25], st_s[5], en_s[5];
    int tid = threadIdx.x;
    if (tid < 25) tr_s[tid] = ctrans[tid];
    if (tid < 5)  { st_s[tid] = cstart[tid]; en_s[tid] = cend[tid]; }
    __syncthreads();

    int b = tid;
    int len = lengths[b];
    const int* tg = labels + (size_t)b * NS;
    const float* eb = em + (size_t)b * NS * NLAB;

    int prev = tg[0];
    float num = st_s[prev] + eb[prev];
    for (int t = 1; t < NS; ++t) {
        if (t < len) {
            int cur = tg[t];
            num += tr_s[prev * NLAB + cur] + eb[t * NLAB + cur];
            prev = cur;
        }
    }
    num += en_s[tg[len - 1]];

    float a[NLAB];
#pragma unroll
    for (int y = 0; y < NLAB; ++y) a[y] = st_s[y] + eb[y];
    for (int t = 1; t < NS; ++t) {
        if (t < len) {
            float na[NLAB];
#pragma unroll
            for (int y = 0; y < NLAB; ++y) {
                float v[NLAB];
#pragma unroll
                for (int x = 0; x < NLAB; ++x) v[x] = a[x] + tr_s[x * NLAB + y];
                na[y] = lse5(v) + eb[t * NLAB + y];
            }
#pragma unroll
            for (int y = 0; y < NLAB; ++y) a[y] = na[y];
        }
    }
    float v[NLAB];
#pragma unroll
    for (int y = 0; y < NLAB; ++y) v[y] = a[y] + en_s[y];
    float denom = lse5(v);

    float llh = num - denom;
#pragma unroll
    for (int off = 32; off > 0; off >>= 1) llh += __shfl_down(llh, off);
    if (tid == 0) outp[0] = -llh * (1.0f / 64.0f);
}

// ----------------------------- launcher --------------------------------------
extern "C" void kernel_launch(void* const* d_in, const int* in_sizes, int n_in,
                              void* d_out, int out_size, void* d_ws, size_t ws_size,
                              hipStream_t stream)
{
    const int*   word_ids = (const int*)d_in[0];
    const int*   char_ids = (const int*)d_in[1];
    const int*   labels   = (const int*)d_in[2];
    const int*   lengths  = (const int*)d_in[3];
    const float* word_emb = (const float*)d_in[4];
    const float* char_emb = (const float*)d_in[5];
    const float* cw3 = (const float*)d_in[6];
    const float* cb3 = (const float*)d_in[7];
    const float* cw4 = (const float*)d_in[8];
    const float* cb4 = (const float*)d_in[9];
    const float* cw5 = (const float*)d_in[10];
    const float* cb5 = (const float*)d_in[11];
    const float* out_w = (const float*)d_in[12];
    const float* out_b = (const float*)d_in[13];
    const float* crf_start = (const float*)d_in[14];
    const float* crf_end   = (const float*)d_in[15];
    const float* crf_trans = (const float*)d_in[16];
    const float* Wih_l0f = (const float*)d_in[17];
    const float* Whh_l0f = (const float*)d_in[18];
    const float* b_l0f   = (const float*)d_in[19];
    const float* Wih_l0r = (const float*)d_in[20];
    const float* Whh_l0r = (const float*)d_in[21];
    const float* b_l0r   = (const float*)d_in[22];
    const float* Wih_l1f = (const float*)d_in[23];
    const float* Whh_l1f = (const float*)d_in[24];
    const float* b_l1f   = (const float*)d_in[25];
    const float* Wih_l1r = (const float*)d_in[26];
    const float* Whh_l1r = (const float*)d_in[27];
    const float* b_l1r   = (const float*)d_in[28];

    // workspace layout (4-byte units), total 24,365,056 = 97.5 MB
    uint32_t* wsu = (uint32_t*)d_ws;
    uint32_t* x0p  = wsu;                         // 8192*225  = 1,843,200
    float*    xg_f = (float*)(wsu + 1843200);     // 8192*1024 = 8,388,608
    float*    xg_r = xg_f + 8388608;
    uint32_t* x1p  = (uint32_t*)(xg_r + 8388608); // 8192*256  = 2,097,152
    uint32_t* x2p  = x1p + 2097152;               // 2,097,152
    float*    em   = (float*)(x2p + 2097152);     // 40,960
    uint32_t* wp0f = (uint32_t*)(em + 40960);     // 225*1024  = 230,400
    uint32_t* wp0r = wp0f + 230400;
    uint32_t* wp1f = wp0r + 230400;               // 256*1024  = 262,144
    uint32_t* wp1r = wp1f + 262144;
    uint32_t* wh0f = wp1r + 262144;               // 131,072 each
    uint32_t* wh0r = wh0f + 131072;
    uint32_t* wh1f = wh0r + 131072;
    uint32_t* wh1r = wh1f + 131072;

    cnn_embed<<<2048, 256, 0, stream>>>(word_ids, char_ids, word_emb, char_emb,
                                        cw3, cb3, cw4, cb4, cw5, cb5, x0p);

    pack_wih<<<900, 256, 0, stream>>>(Wih_l0f, COMB, wp0f);
    pack_wih<<<900, 256, 0, stream>>>(Wih_l0r, COMB, wp0r);
    pack_wih<<<1024, 256, 0, stream>>>(Wih_l1f, 512, wp1f);
    pack_wih<<<1024, 256, 0, stream>>>(Wih_l1r, 512, wp1r);
    pack_whh<<<512, 256, 0, stream>>>(Whh_l0f, wh0f);
    pack_whh<<<512, 256, 0, stream>>>(Whh_l0r, wh0r);
    pack_whh<<<512, 256, 0, stream>>>(Whh_l1f, wh1f);
    pack_whh<<<512, 256, 0, stream>>>(Whh_l1r, wh1r);

    dim3 gGemm(64, 16);
    gemm_f16<<<gGemm, 256, 0, stream>>>(x0p, 225, wp0f, wp0r, b_l0f, b_l0r, xg_f, xg_r);
    lstm_rec3<<<64, 512, 0, stream>>>(xg_f, xg_r, wh0f, wh0r, x1p);

    gemm_f16<<<gGemm, 256, 0, stream>>>(x1p, 256, wp1f, wp1r, b_l1f, b_l1r, xg_f, xg_r);
    lstm_rec3<<<64, 512, 0, stream>>>(xg_f, xg_r, wh1f, wh1r, x2p);

    emis_kernel<<<32, 256, 0, stream>>>(x2p, out_w, out_b, em);
    crf_kernel<<<1, 64, 0, stream>>>(em, labels, lengths, crf_start, crf_end, crf_trans,
                                     (float*)d_out);
}